// Round 7
// baseline (27.121 us; speedup 1.0000x reference)
//
#include <hip/hip_runtime.h>

// x,y: [B=8, T=2048, C=1024] fp32.
// -mean(einsum('itj,itl->ijl', x, y)) ==
//   -(1/(B*C*C)) * sum_{rows} rowsum(x_row) * rowsum(y_row)
//
// Round 7: 1 row per wave (16384 waves, 4096 blocks x 256 thr).
//  - 8 float4 loads per lane issued before any dependent use (low VGPR
//    pressure -> compiler keeps them all in flight);
//  - 2 interleaved 64-lane butterflies per wave (vs 4 in round 6);
//  - 2x wave oversubscription: second-generation waves issue loads while
//    first-generation waves sit in their reduction tail.
#define N_C    1024
#define DENOM  (8.0 * 1024.0 * 1024.0)  // B*C*C

#define THREADS 256
#define BLOCKS  4096
#define WPB     (THREADS / 64)            // 4 waves/block, 1 row each

__global__ __launch_bounds__(THREADS)
void corr_partial(const float* __restrict__ x,
                  const float* __restrict__ y,
                  double* __restrict__ partials) {
    const int lane = threadIdx.x & 63;
    const int w    = threadIdx.x >> 6;
    const size_t row = (size_t)blockIdx.x * WPB + w;   // 0..16383

    const float4* xr = (const float4*)(x + row * N_C);
    const float4* yr = (const float4*)(y + row * N_C);

    // Issue all 8 coalesced 16B loads up front.
    float4 a0 = xr[lane +   0], a1 = xr[lane +  64],
           a2 = xr[lane + 128], a3 = xr[lane + 192];
    float4 b0 = yr[lane +   0], b1 = yr[lane +  64],
           b2 = yr[lane + 128], b3 = yr[lane + 192];

    float sx = ((a0.x + a0.y) + (a0.z + a0.w)) + ((a1.x + a1.y) + (a1.z + a1.w))
             + ((a2.x + a2.y) + (a2.z + a2.w)) + ((a3.x + a3.y) + (a3.z + a3.w));
    float sy = ((b0.x + b0.y) + (b0.z + b0.w)) + ((b1.x + b1.y) + (b1.z + b1.w))
             + ((b2.x + b2.y) + (b2.z + b2.w)) + ((b3.x + b3.y) + (b3.z + b3.w));

    // Two independent interleaved 64-lane butterflies.
    #pragma unroll
    for (int off = 32; off > 0; off >>= 1) {
        sx += __shfl_xor(sx, off, 64);
        sy += __shfl_xor(sy, off, 64);
    }

    // Fold the block's 4 wave-partials: 32 B LDS, one cheap barrier.
    __shared__ double sdata[WPB];
    if (lane == 0) sdata[w] = (double)sx * (double)sy;
    __syncthreads();
    if (threadIdx.x == 0)
        partials[blockIdx.x] = (sdata[0] + sdata[1]) + (sdata[2] + sdata[3]);
}

__global__ __launch_bounds__(256)
void corr_final_reduce(const double* __restrict__ partials,
                       float* __restrict__ out) {
    const int lane = threadIdx.x & 63;
    const int w    = threadIdx.x >> 6;
    // 4096 doubles / 256 threads = 16 doubles = 8 double2 per thread.
    const double2* p = (const double2*)partials;
    double acc = 0.0;
    #pragma unroll
    for (int k = 0; k < 8; ++k) {
        double2 v = p[threadIdx.x + 256 * k];   // coalesced
        acc += v.x + v.y;
    }
    #pragma unroll
    for (int off = 32; off > 0; off >>= 1)
        acc += __shfl_xor(acc, off, 64);
    __shared__ double sdata[4];
    if (lane == 0) sdata[w] = acc;
    __syncthreads();
    if (threadIdx.x == 0)
        out[0] = (float)(-((sdata[0] + sdata[1]) + (sdata[2] + sdata[3])) / DENOM);
}

extern "C" void kernel_launch(void* const* d_in, const int* in_sizes, int n_in,
                              void* d_out, int out_size, void* d_ws, size_t ws_size,
                              hipStream_t stream) {
    const float* x = (const float*)d_in[0];
    const float* y = (const float*)d_in[1];
    float* out = (float*)d_out;
    double* partials = (double*)d_ws;   // BLOCKS * 8 = 32 KiB scratch

    corr_partial<<<BLOCKS, THREADS, 0, stream>>>(x, y, partials);
    corr_final_reduce<<<1, 256, 0, stream>>>(partials, out);
}